// Round 4
// baseline (321.926 us; speedup 1.0000x reference)
//
#include <hip/hip_runtime.h>

// B=131072, P=3, D=128, H=4, DH=32 ; fp32 in/out.
// Round 4: persistent blocks + x-prefetch software pipeline.
//   pre-kernel: pack W_K|W_Q|W_V (384x128) and W_O (128x128) as bf16 MFMA
//               B-fragments into d_ws (131 KB, L2-resident).
//   main kernel: 1024 persistent blocks x 8 groups of 48 rows. One 48x392 u16
//   LDS buffer: x lives in cols[0:128) (k-slots), qkv overwrites it in Phase A,
//   z goes into dead q-slots cols[128:256), and next group's x is written back
//   into cols[0:128) during Phase C (those cols are dead after Phase B).
//   Next-group x loads are issued right after the a-fragment pull, so HBM
//   latency hides under phases A-C.
// mfma_f32_16x16x32_bf16 layouts (learn_hip m89-verified):
//   A: lane l holds A[l&15][(l>>4)*8 + j] ; B: lane l holds B[(l>>4)*8+j][l&15]
//   C/D: col = l&15, row = (l>>4)*4 + reg

typedef __attribute__((ext_vector_type(8))) __bf16 bf16x8;
typedef __attribute__((ext_vector_type(4))) __bf16 bf16x4;
typedef __attribute__((ext_vector_type(4))) float f32x4;
typedef __attribute__((ext_vector_type(8))) unsigned short u16x8;

#define BATCH 131072
#define PP 3
#define DD 128
#define RB 48            // rows per group = 16 batches * 3
#define BB 16
#define THREADS 256
#define QS_STRIDE 392    // u16; 784 B rows
#define NGROUP (BATCH * PP / RB)   // 8192
#define GRID 1024
#define NITER (NGROUP / GRID)      // 8

#define NFRAG_QKV (24 * 4)
#define NFRAG_WO (8 * 4)
#define QKV_PACK_ELEMS (NFRAG_QKV * 64 * 8)   // 49152 bf16
#define WO_PACK_ELEMS (NFRAG_WO * 64 * 8)     // 16384 bf16

__device__ __forceinline__ unsigned short f2bf(float f) {
    union { __bf16 h; unsigned short u; } c;
    c.h = (__bf16)f;                      // native RNE, fuses to v_cvt_pk_bf16_f32
    return c.u;
}
__device__ __forceinline__ float bf2f(unsigned short s) {
    return __uint_as_float(((unsigned int)s) << 16);
}

// ---- weight pre-pack --------------------------------------------------------
__global__ __launch_bounds__(256)
void pack_weights(const float* __restrict__ Wk, const float* __restrict__ Wq,
                  const float* __restrict__ Wv, const float* __restrict__ Wo,
                  unsigned short* __restrict__ pk)
{
    int e = blockIdx.x * 256 + threadIdx.x;     // 0 .. 65535
    int j = e & 7;
    int lane = (e >> 3) & 63;
    int lr = lane & 15, g = lane >> 4;
    float v;
    if (e < QKV_PACK_ELEMS) {
        int ks = (e >> 9) & 3;
        int nt = e >> 11;                        // 0..23
        int n = nt * 16 + lr;                    // 0..127 k, 128..255 q, 256..383 v
        int k = ks * 32 + g * 8 + j;
        const float* base = (n < 128) ? Wk : (n < 256 ? Wq : Wv);
        v = base[(size_t)(n & 127) * DD + k];
    } else {
        int e2 = e - QKV_PACK_ELEMS;
        int ks = (e2 >> 9) & 3;
        int nt = e2 >> 11;                       // 0..7
        int d = nt * 16 + lr;
        int f = ks * 32 + g * 8 + j;
        v = Wo[(size_t)d * DD + f];
    }
    pk[e] = f2bf(v);
}

// ---- fused attention, persistent + pipelined --------------------------------
__global__ __launch_bounds__(THREADS, 4)
void attn_mfma(const float* __restrict__ x,
               const unsigned short* __restrict__ wpk,
               float* __restrict__ out)
{
    __shared__ unsigned short buf[RB * QS_STRIDE];   // 37632 B

    const int t = threadIdx.x;
    const int wave = t >> 6, lane = t & 63;
    const int lr = lane & 15, g = lane >> 4;
    const size_t grp0 = (size_t)blockIdx.x * NITER;

    const float4* xg = (const float4*)x;   // group gi starts at float4 index gi*1536

    // ---- prologue: stage x(grp0) -> bf16 LDS cols[0:128)
    {
        #pragma unroll
        for (int j = 0; j < 6; ++j) {
            int i = t + j * 256;                // 0..1535
            float4 v = xg[grp0 * 1536 + i];
            int row = i >> 5, c = (i & 31) * 4;
            bf16x4 b;
            b[0] = (__bf16)v.x; b[1] = (__bf16)v.y; b[2] = (__bf16)v.z; b[3] = (__bf16)v.w;
            *(bf16x4*)&buf[row * QS_STRIDE + c] = b;
        }
    }

    for (int it = 0; it < NITER; ++it) {
        const size_t grp = grp0 + it;
        __syncthreads();                         // x(it) visible

        // ---- pull x A-fragments into registers
        bf16x8 a[3][4];
        #pragma unroll
        for (int m = 0; m < 3; ++m)
            #pragma unroll
            for (int k = 0; k < 4; ++k)
                a[m][k] = *(const bf16x8*)&buf[(m * 16 + lr) * QS_STRIDE + k * 32 + g * 8];

        // ---- issue next group's x loads (latency hides under phases A-C)
        float4 xr[6];
        if (it + 1 < NITER) {
            #pragma unroll
            for (int j = 0; j < 6; ++j)
                xr[j] = xg[(grp + 1) * 1536 + t + j * 256];
        }
        __syncthreads();                         // a-frag reads done

        // ---- Phase A: qkv[48][384] = x @ W^T  (wave owns 6 n-tiles)
        {
            const bf16x8* bp = (const bf16x8*)wpk;    // frag (nt*4+k)*64+lane
            const int ntb = wave * 6;
            const f32x4 zero4 = {0.f, 0.f, 0.f, 0.f};
            #pragma unroll
            for (int n6 = 0; n6 < 6; ++n6) {
                int nt = ntb + n6;
                bf16x8 b[4];
                #pragma unroll
                for (int k = 0; k < 4; ++k) b[k] = bp[(nt * 4 + k) * 64 + lane];
                f32x4 acc[3];
                #pragma unroll
                for (int m = 0; m < 3; ++m) acc[m] = zero4;
                #pragma unroll
                for (int k = 0; k < 4; ++k)
                    #pragma unroll
                    for (int m = 0; m < 3; ++m)
                        acc[m] = __builtin_amdgcn_mfma_f32_16x16x32_bf16(a[m][k], b[k], acc[m], 0, 0, 0);
                #pragma unroll
                for (int m = 0; m < 3; ++m)
                    #pragma unroll
                    for (int r = 0; r < 4; ++r)
                        buf[(m * 16 + g * 4 + r) * QS_STRIDE + nt * 16 + lr] = f2bf(acc[m][r]);
            }
        }
        __syncthreads();

        // ---- Phase B: causal attention, thread per (batch, head, qpos)
        if (t < BB * 4 * PP) {                   // 192 threads
            const int lb = t / 12;
            const int rem = t % 12;
            const int hd = rem / 3;
            const int q = rem % 3;
            const int rq = lb * 3 + q;
            const int co = hd * 32;

            float qv[32];
            #pragma unroll
            for (int c = 0; c < 4; ++c) {
                u16x8 u = *(const u16x8*)&buf[rq * QS_STRIDE + 128 + co + c * 8];
                #pragma unroll
                for (int j = 0; j < 8; ++j) qv[c * 8 + j] = bf2f(u[j]);
            }
            float sc[3];
            float mx = -1e30f;
            #pragma unroll
            for (int p = 0; p < 3; ++p) {
                if (p <= q) {
                    float s = 0.f;
                    #pragma unroll
                    for (int c = 0; c < 4; ++c) {
                        u16x8 u = *(const u16x8*)&buf[(lb * 3 + p) * QS_STRIDE + co + c * 8];
                        #pragma unroll
                        for (int j = 0; j < 8; ++j) s += bf2f(u[j]) * qv[c * 8 + j];
                    }
                    s *= 0.17677669529663687f;    // 1/sqrt(32)
                    sc[p] = s;
                    mx = fmaxf(mx, s);
                }
            }
            float l = 0.f;
            #pragma unroll
            for (int p = 0; p < 3; ++p)
                if (p <= q) { sc[p] = __expf(sc[p] - mx); l += sc[p]; }
            const float inv = 1.f / l;

            #pragma unroll
            for (int c = 0; c < 4; ++c) {
                float z[8];
                #pragma unroll
                for (int j = 0; j < 8; ++j) z[j] = 0.f;
                #pragma unroll
                for (int p = 0; p < 3; ++p) {
                    if (p <= q) {
                        u16x8 u = *(const u16x8*)&buf[(lb * 3 + p) * QS_STRIDE + 256 + co + c * 8];
                        #pragma unroll
                        for (int j = 0; j < 8; ++j) z[j] += sc[p] * bf2f(u[j]);
                    }
                }
                u16x8 o;
                #pragma unroll
                for (int j = 0; j < 8; ++j) o[j] = f2bf(z[j] * inv);
                *(u16x8*)&buf[rq * QS_STRIDE + 128 + co + c * 8] = o;  // own q-slot
            }
        }
        __syncthreads();

        // ---- Phase C: out = z @ Wo^T  (z at col offset 128)
        {
            bf16x8 az[3][4];
            #pragma unroll
            for (int m = 0; m < 3; ++m)
                #pragma unroll
                for (int k = 0; k < 4; ++k)
                    az[m][k] = *(const bf16x8*)&buf[(m * 16 + lr) * QS_STRIDE + 128 + k * 32 + g * 8];

            const bf16x8* wop = (const bf16x8*)(wpk + QKV_PACK_ELEMS);
            const f32x4 zero4 = {0.f, 0.f, 0.f, 0.f};
            #pragma unroll
            for (int n2 = 0; n2 < 2; ++n2) {
                int nt = wave * 2 + n2;
                bf16x8 b[4];
                #pragma unroll
                for (int k = 0; k < 4; ++k) b[k] = wop[(nt * 4 + k) * 64 + lane];
                f32x4 acc[3];
                #pragma unroll
                for (int m = 0; m < 3; ++m) acc[m] = zero4;
                #pragma unroll
                for (int k = 0; k < 4; ++k)
                    #pragma unroll
                    for (int m = 0; m < 3; ++m)
                        acc[m] = __builtin_amdgcn_mfma_f32_16x16x32_bf16(az[m][k], b[k], acc[m], 0, 0, 0);
                #pragma unroll
                for (int m = 0; m < 3; ++m)
                    #pragma unroll
                    for (int r = 0; r < 4; ++r) {
                        size_t rg = grp * RB + (size_t)(m * 16 + g * 4 + r);
                        out[rg * DD + nt * 16 + lr] = acc[m][r];
                    }
            }
        }

        // ---- write prefetched x into cols[0:128) (dead after Phase B barrier)
        if (it + 1 < NITER) {
            #pragma unroll
            for (int j = 0; j < 6; ++j) {
                int i = t + j * 256;
                int row = i >> 5, c = (i & 31) * 4;
                bf16x4 b;
                b[0] = (__bf16)xr[j].x; b[1] = (__bf16)xr[j].y;
                b[2] = (__bf16)xr[j].z; b[3] = (__bf16)xr[j].w;
                *(bf16x4*)&buf[row * QS_STRIDE + c] = b;
            }
        }
    }
}

extern "C" void kernel_launch(void* const* d_in, const int* in_sizes, int n_in,
                              void* d_out, int out_size, void* d_ws, size_t ws_size,
                              hipStream_t stream) {
    const float* x  = (const float*)d_in[0];
    const float* Wk = (const float*)d_in[1];
    const float* Wq = (const float*)d_in[2];
    const float* Wv = (const float*)d_in[3];
    const float* Wo = (const float*)d_in[4];
    float* out = (float*)d_out;
    unsigned short* pk = (unsigned short*)d_ws;   // needs 131072 B

    pack_weights<<<(QKV_PACK_ELEMS + WO_PACK_ELEMS) / 256, 256, 0, stream>>>(Wk, Wq, Wv, Wo, pk);
    attn_mfma<<<GRID, THREADS, 0, stream>>>(x, pk, out);
}

// Round 5
// 163.329 us; speedup vs baseline: 1.9710x; 1.9710x over previous
//
#include <hip/hip_runtime.h>

// B=131072, P=3, D=128, H=4, DH=32 ; fp32 in/out.
// Round 5: persistent blocks + ASYNC x-prefetch via global_load_lds (zero
// VGPR cost -> no spill, the round-4 failure), + all weight B-fragments
// hoisted into registers across the 16-iteration loop (128 VGPR; weights are
// iteration-invariant, so phases A/C are pure-register MFMA).
//   LDS: xs = 48x128 fp32 x-stage (global-side XOR-swizzled chunks so
//        a-frag ds_read_b128 is bank-uniform), qk = 48x392 bf16 qkv/z buffer.
//   Pipeline per iter: barrier(vmcnt drain: x ready) -> a-frag pull ->
//   barrier -> issue async gload_lds for next x -> A (MFMA) -> barrier ->
//   B (scalar attention) -> barrier -> C (MFMA + stores).
// mfma_f32_16x16x32_bf16: A: lane l holds A[l&15][(l>>4)*8+j];
//   B: lane l holds B[(l>>4)*8+j][l&15]; C/D: col=l&15, row=(l>>4)*4+reg.

typedef __attribute__((ext_vector_type(8))) __bf16 bf16x8;
typedef __attribute__((ext_vector_type(4))) float f32x4;
typedef __attribute__((ext_vector_type(8))) unsigned short u16x8;

#define BATCH 131072
#define PP 3
#define DD 128
#define RB 48            // rows per group = 16 batches * 3
#define BB 16
#define THREADS 256
#define QS_STRIDE 392    // u16
#define NGROUP (BATCH * PP / RB)   // 8192
#define GRID 512
#define NITER (NGROUP / GRID)      // 16

#define NFRAG_QKV (24 * 4)
#define NFRAG_WO (8 * 4)
#define QKV_PACK_ELEMS (NFRAG_QKV * 64 * 8)   // 49152 bf16
#define WO_PACK_ELEMS (NFRAG_WO * 64 * 8)     // 16384 bf16

__device__ __forceinline__ unsigned short f2bf(float f) {
    union { __bf16 h; unsigned short u; } c;
    c.h = (__bf16)f;
    return c.u;
}
__device__ __forceinline__ float bf2f(unsigned short s) {
    return __uint_as_float(((unsigned int)s) << 16);
}
__device__ __forceinline__ bf16x8 cvt8(float4 lo, float4 hi) {
    bf16x8 r;
    r[0] = (__bf16)lo.x; r[1] = (__bf16)lo.y; r[2] = (__bf16)lo.z; r[3] = (__bf16)lo.w;
    r[4] = (__bf16)hi.x; r[5] = (__bf16)hi.y; r[6] = (__bf16)hi.z; r[7] = (__bf16)hi.w;
    return r;
}

// ---- weight pre-pack --------------------------------------------------------
__global__ __launch_bounds__(256)
void pack_weights(const float* __restrict__ Wk, const float* __restrict__ Wq,
                  const float* __restrict__ Wv, const float* __restrict__ Wo,
                  unsigned short* __restrict__ pk)
{
    int e = blockIdx.x * 256 + threadIdx.x;     // 0 .. 65535
    int j = e & 7;
    int lane = (e >> 3) & 63;
    int lr = lane & 15, g = lane >> 4;
    float v;
    if (e < QKV_PACK_ELEMS) {
        int ks = (e >> 9) & 3;
        int nt = e >> 11;                        // 0..23
        int n = nt * 16 + lr;                    // 0..127 k, 128..255 q, 256..383 v
        int k = ks * 32 + g * 8 + j;
        const float* base = (n < 128) ? Wk : (n < 256 ? Wq : Wv);
        v = base[(size_t)(n & 127) * DD + k];
    } else {
        int e2 = e - QKV_PACK_ELEMS;
        int ks = (e2 >> 9) & 3;
        int nt = e2 >> 11;                       // 0..7
        int d = nt * 16 + lr;
        int f = ks * 32 + g * 8 + j;
        v = Wo[(size_t)d * DD + f];
    }
    pk[e] = f2bf(v);
}

// ---- fused attention, persistent + async LDS prefetch -----------------------
__global__ __launch_bounds__(THREADS, 2)
void attn_mfma(const float* __restrict__ x,
               const unsigned short* __restrict__ wpk,
               float* __restrict__ out)
{
    __shared__ float xs[RB * DD];                  // 24576 B, swizzled chunks
    __shared__ unsigned short qk[RB * QS_STRIDE];  // 37632 B

    const int t = threadIdx.x;
    const int wave = t >> 6, lane = t & 63;
    const int lr = lane & 15, g = lane >> 4;
    const size_t grp0 = (size_t)blockIdx.x * NITER;

    // ---- hoist ALL weight B-fragments into registers (iteration-invariant)
    bf16x8 bA[6][4];   // this wave's 6 qkv n-tiles
    {
        const bf16x8* bp = (const bf16x8*)wpk;
        #pragma unroll
        for (int n6 = 0; n6 < 6; ++n6)
            #pragma unroll
            for (int k = 0; k < 4; ++k)
                bA[n6][k] = bp[((wave * 6 + n6) * 4 + k) * 64 + lane];
    }
    bf16x8 bC[2][4];   // this wave's 2 Wo n-tiles
    {
        const bf16x8* wop = (const bf16x8*)(wpk + QKV_PACK_ELEMS);
        #pragma unroll
        for (int n2 = 0; n2 < 2; ++n2)
            #pragma unroll
            for (int k = 0; k < 4; ++k)
                bC[n2][k] = wop[((wave * 2 + n2) * 4 + k) * 64 + lane];
    }

    // ---- async x-stage: 6 x global_load_lds(16B) per wave covers 12 rows.
    // LDS is linear (row*512B + pos*16B); global chunk is pre-swizzled
    // c = pos ^ (row&7) so a-frag ds_read_b128 hits banks uniformly.
    auto issue_x = [&](size_t grp) {
        const float* gbase = x + grp * (size_t)(RB * DD);
        #pragma unroll
        for (int j = 0; j < 6; ++j) {
            int row = wave * 12 + 2 * j + (lane >> 5);
            int p = lane & 31;
            int c = p ^ (row & 7);
            const float* gp = gbase + row * DD + c * 4;
            float* lp = &xs[(wave * 12 + 2 * j) * DD];   // wave-uniform base
            __builtin_amdgcn_global_load_lds(
                (const __attribute__((address_space(1))) void*)gp,
                (__attribute__((address_space(3))) void*)lp, 16, 0, 0);
        }
    };

    issue_x(grp0);   // prologue prefetch

    for (int it = 0; it < NITER; ++it) {
        const size_t grp = grp0 + it;
        __syncthreads();   // vmcnt(0) drain: x(it) landed; qk safe to rewrite

        // ---- pull x A-fragments (swizzled fp32 chunks -> bf16 regs)
        bf16x8 a[3][4];
        #pragma unroll
        for (int m = 0; m < 3; ++m)
            #pragma unroll
            for (int k = 0; k < 4; ++k) {
                int row = m * 16 + lr;
                int c0 = k * 8 + g * 2;
                float4 lo = *(const float4*)&xs[row * DD + ((c0 ^ (lr & 7)) * 4)];
                float4 hi = *(const float4*)&xs[row * DD + (((c0 + 1) ^ (lr & 7)) * 4)];
                a[m][k] = cvt8(lo, hi);
            }
        __syncthreads();   // xs free for next prefetch

        if (it + 1 < NITER) issue_x(grp + 1);   // async, zero VGPR held

        // ---- Phase A: qkv[48][384] = x @ W^T (pure-register MFMA)
        {
            const f32x4 zero4 = {0.f, 0.f, 0.f, 0.f};
            #pragma unroll
            for (int n6 = 0; n6 < 6; ++n6) {
                int nt = wave * 6 + n6;
                f32x4 acc[3];
                #pragma unroll
                for (int m = 0; m < 3; ++m) acc[m] = zero4;
                #pragma unroll
                for (int k = 0; k < 4; ++k)
                    #pragma unroll
                    for (int m = 0; m < 3; ++m)
                        acc[m] = __builtin_amdgcn_mfma_f32_16x16x32_bf16(a[m][k], bA[n6][k], acc[m], 0, 0, 0);
                #pragma unroll
                for (int m = 0; m < 3; ++m)
                    #pragma unroll
                    for (int r = 0; r < 4; ++r)
                        qk[(m * 16 + g * 4 + r) * QS_STRIDE + nt * 16 + lr] = f2bf(acc[m][r]);
            }
        }
        __syncthreads();

        // ---- Phase B: causal attention, thread per (batch, head, qpos)
        if (t < BB * 4 * PP) {                   // 192 threads
            const int lb = t / 12;
            const int rem = t % 12;
            const int hd = rem / 3;
            const int q = rem % 3;
            const int rq = lb * 3 + q;
            const int co = hd * 32;

            float qv[32];
            #pragma unroll
            for (int c = 0; c < 4; ++c) {
                u16x8 u = *(const u16x8*)&qk[rq * QS_STRIDE + 128 + co + c * 8];
                #pragma unroll
                for (int j = 0; j < 8; ++j) qv[c * 8 + j] = bf2f(u[j]);
            }
            float sc[3];
            float mx = -1e30f;
            #pragma unroll
            for (int p = 0; p < 3; ++p) {
                if (p <= q) {
                    float s = 0.f;
                    #pragma unroll
                    for (int c = 0; c < 4; ++c) {
                        u16x8 u = *(const u16x8*)&qk[(lb * 3 + p) * QS_STRIDE + co + c * 8];
                        #pragma unroll
                        for (int j = 0; j < 8; ++j) s += bf2f(u[j]) * qv[c * 8 + j];
                    }
                    s *= 0.17677669529663687f;    // 1/sqrt(32)
                    sc[p] = s;
                    mx = fmaxf(mx, s);
                }
            }
            float l = 0.f;
            #pragma unroll
            for (int p = 0; p < 3; ++p)
                if (p <= q) { sc[p] = __expf(sc[p] - mx); l += sc[p]; }
            const float inv = 1.f / l;

            #pragma unroll
            for (int c = 0; c < 4; ++c) {
                float z[8];
                #pragma unroll
                for (int j = 0; j < 8; ++j) z[j] = 0.f;
                #pragma unroll
                for (int p = 0; p < 3; ++p) {
                    if (p <= q) {
                        u16x8 u = *(const u16x8*)&qk[(lb * 3 + p) * QS_STRIDE + 256 + co + c * 8];
                        #pragma unroll
                        for (int j = 0; j < 8; ++j) z[j] += sc[p] * bf2f(u[j]);
                    }
                }
                u16x8 o;
                #pragma unroll
                for (int j = 0; j < 8; ++j) o[j] = f2bf(z[j] * inv);
                *(u16x8*)&qk[rq * QS_STRIDE + 128 + co + c * 8] = o;  // own q-slot
            }
        }
        __syncthreads();

        // ---- Phase C: out = z @ Wo^T (z at qk col offset 128; weights in regs)
        {
            bf16x8 az[3][4];
            #pragma unroll
            for (int m = 0; m < 3; ++m)
                #pragma unroll
                for (int k = 0; k < 4; ++k)
                    az[m][k] = *(const bf16x8*)&qk[(m * 16 + lr) * QS_STRIDE + 128 + k * 32 + g * 8];

            const f32x4 zero4 = {0.f, 0.f, 0.f, 0.f};
            #pragma unroll
            for (int n2 = 0; n2 < 2; ++n2) {
                int nt = wave * 2 + n2;
                f32x4 acc[3];
                #pragma unroll
                for (int m = 0; m < 3; ++m) acc[m] = zero4;
                #pragma unroll
                for (int k = 0; k < 4; ++k)
                    #pragma unroll
                    for (int m = 0; m < 3; ++m)
                        acc[m] = __builtin_amdgcn_mfma_f32_16x16x32_bf16(az[m][k], bC[n2][k], acc[m], 0, 0, 0);
                #pragma unroll
                for (int m = 0; m < 3; ++m)
                    #pragma unroll
                    for (int r = 0; r < 4; ++r) {
                        size_t rg = grp * RB + (size_t)(m * 16 + g * 4 + r);
                        out[rg * DD + nt * 16 + lr] = acc[m][r];
                    }
            }
        }
    }
}

extern "C" void kernel_launch(void* const* d_in, const int* in_sizes, int n_in,
                              void* d_out, int out_size, void* d_ws, size_t ws_size,
                              hipStream_t stream) {
    const float* x  = (const float*)d_in[0];
    const float* Wk = (const float*)d_in[1];
    const float* Wq = (const float*)d_in[2];
    const float* Wv = (const float*)d_in[3];
    const float* Wo = (const float*)d_in[4];
    float* out = (float*)d_out;
    unsigned short* pk = (unsigned short*)d_ws;   // needs 131072 B

    pack_weights<<<(QKV_PACK_ELEMS + WO_PACK_ELEMS) / 256, 256, 0, stream>>>(Wk, Wq, Wv, Wo, pk);
    attn_mfma<<<GRID, THREADS, 0, stream>>>(x, pk, out);
}

// Round 6
// 134.734 us; speedup vs baseline: 2.3894x; 1.2122x over previous
//
#include <hip/hip_runtime.h>

// B=131072, P=3, D=128, H=4, DH=32 ; fp32 in/out.
// Round 6: r2 structure (the 112 µs best) with 512 threads per 48-row group.
//   Rationale: latency-bound at ~12 waves/CU; LDS/row and threads/row were
//   invariant -> double threads/row: 3 blocks/CU x 8 waves = 24 waves/CU.
//   Same 3-barrier phase chain, same LDS (50.7 KB), half per-thread work.
//   Restored from r2: nontemporal out stores, b-frag double-buffer.
//   Kept from r3+: native (__bf16) pk converts.
// mfma_f32_16x16x32_bf16: A: lane l holds A[l&15][(l>>4)*8+j];
//   B: lane l holds B[(l>>4)*8+j][l&15]; C/D: col=l&15, row=(l>>4)*4+reg.

typedef __attribute__((ext_vector_type(8))) __bf16 bf16x8;
typedef __attribute__((ext_vector_type(4))) float f32x4;
typedef __attribute__((ext_vector_type(8))) unsigned short u16x8;
typedef __attribute__((ext_vector_type(4))) unsigned short u16x4;

#define BATCH 131072
#define PP 3
#define DD 128
#define RB 48            // rows per block = 16 batches * 3
#define BB 16
#define THREADS 512      // 8 waves
#define XS_STRIDE 136    // u16; 272 B rows
#define QS_STRIDE 392    // u16; 784 B rows

#define NFRAG_QKV (24 * 4)
#define NFRAG_WO (8 * 4)
#define QKV_PACK_ELEMS (NFRAG_QKV * 64 * 8)   // 49152 bf16
#define WO_PACK_ELEMS (NFRAG_WO * 64 * 8)     // 16384 bf16

__device__ __forceinline__ unsigned short f2bf(float f) {
    union { __bf16 h; unsigned short u; } c;
    c.h = (__bf16)f;                      // native RNE (v_cvt_pk_bf16_f32)
    return c.u;
}
__device__ __forceinline__ float bf2f(unsigned short s) {
    return __uint_as_float(((unsigned int)s) << 16);
}

// ---- weight pre-pack --------------------------------------------------------
__global__ __launch_bounds__(256)
void pack_weights(const float* __restrict__ Wk, const float* __restrict__ Wq,
                  const float* __restrict__ Wv, const float* __restrict__ Wo,
                  unsigned short* __restrict__ pk)
{
    int e = blockIdx.x * 256 + threadIdx.x;     // 0 .. 65535
    int j = e & 7;
    int lane = (e >> 3) & 63;
    int lr = lane & 15, g = lane >> 4;
    float v;
    if (e < QKV_PACK_ELEMS) {
        int ks = (e >> 9) & 3;
        int nt = e >> 11;                        // 0..23
        int n = nt * 16 + lr;                    // 0..127 k, 128..255 q, 256..383 v
        int k = ks * 32 + g * 8 + j;
        const float* base = (n < 128) ? Wk : (n < 256 ? Wq : Wv);
        v = base[(size_t)(n & 127) * DD + k];
    } else {
        int e2 = e - QKV_PACK_ELEMS;
        int ks = (e2 >> 9) & 3;
        int nt = e2 >> 11;                       // 0..7
        int d = nt * 16 + lr;
        int f = ks * 32 + g * 8 + j;
        v = Wo[(size_t)d * DD + f];
    }
    pk[e] = f2bf(v);
}

// ---- fused attention --------------------------------------------------------
__global__ __launch_bounds__(THREADS, 6)
void attn_mfma(const float* __restrict__ x,
               const unsigned short* __restrict__ wpk,
               float* __restrict__ out)
{
    __shared__ unsigned short xs[RB * XS_STRIDE];  // 13056 B: bf16 x, later z
    __shared__ unsigned short qk[RB * QS_STRIDE];  // 37632 B: bf16 qkv

    const int t = threadIdx.x;
    const int wave = t >> 6, lane = t & 63;
    const int lr = lane & 15, g = lane >> 4;
    const size_t row0 = (size_t)blockIdx.x * RB;

    // ---- stage x: 48 rows x 128 fp32 -> bf16, coalesced; 3 float4 per thread
    {
        const float4* xg = (const float4*)(x + row0 * DD);
        #pragma unroll
        for (int j = 0; j < 3; ++j) {
            int i = t + j * THREADS;               // 0..1535
            float4 v = xg[i];
            int row = i >> 5, c = (i & 31) * 4;
            u16x4 b;
            b[0] = f2bf(v.x); b[1] = f2bf(v.y); b[2] = f2bf(v.z); b[3] = f2bf(v.w);
            *(u16x4*)&xs[row * XS_STRIDE + c] = b;
        }
    }
    __syncthreads();

    // ---- Phase A: qkv[48][384] = x @ W^T  (8 waves x 3 n-tiles)
    {
        bf16x8 a[3][4];
        #pragma unroll
        for (int m = 0; m < 3; ++m)
            #pragma unroll
            for (int k = 0; k < 4; ++k)
                a[m][k] = *(const bf16x8*)&xs[(m * 16 + lr) * XS_STRIDE + k * 32 + g * 8];

        const bf16x8* bp = (const bf16x8*)wpk;    // frag (nt*4+k)*64+lane
        const int ntb = wave * 3;
        bf16x8 bcur[4], bnxt[4];
        #pragma unroll
        for (int k = 0; k < 4; ++k) bcur[k] = bp[(ntb * 4 + k) * 64 + lane];

        const f32x4 zero4 = {0.f, 0.f, 0.f, 0.f};
        #pragma unroll
        for (int n3 = 0; n3 < 3; ++n3) {
            int nt = ntb + n3;
            if (n3 < 2) {
                #pragma unroll
                for (int k = 0; k < 4; ++k) bnxt[k] = bp[((nt + 1) * 4 + k) * 64 + lane];
            }
            f32x4 acc[3];
            #pragma unroll
            for (int m = 0; m < 3; ++m) acc[m] = zero4;
            #pragma unroll
            for (int k = 0; k < 4; ++k)
                #pragma unroll
                for (int m = 0; m < 3; ++m)
                    acc[m] = __builtin_amdgcn_mfma_f32_16x16x32_bf16(a[m][k], bcur[k], acc[m], 0, 0, 0);
            #pragma unroll
            for (int m = 0; m < 3; ++m)
                #pragma unroll
                for (int r = 0; r < 4; ++r)
                    qk[(m * 16 + g * 4 + r) * QS_STRIDE + nt * 16 + lr] = f2bf(acc[m][r]);
            if (n3 < 2) {
                #pragma unroll
                for (int k = 0; k < 4; ++k) bcur[k] = bnxt[k];
            }
        }
    }
    __syncthreads();

    // ---- Phase B: causal attention, thread per (batch, head, qpos): 192 threads
    // z written into xs (x dead: a-frags are in registers, barrier passed)
    if (t < BB * 4 * PP) {
        const int lb = t / 12;
        const int rem = t % 12;
        const int hd = rem / 3;
        const int q = rem % 3;
        const int rq = lb * 3 + q;
        const int co = hd * 32;

        float qv[32];
        #pragma unroll
        for (int c = 0; c < 4; ++c) {
            u16x8 u = *(const u16x8*)&qk[rq * QS_STRIDE + 128 + co + c * 8];
            #pragma unroll
            for (int j = 0; j < 8; ++j) qv[c * 8 + j] = bf2f(u[j]);
        }
        float sc[3];
        float mx = -1e30f;
        #pragma unroll
        for (int p = 0; p < 3; ++p) {
            if (p <= q) {
                float s = 0.f;
                #pragma unroll
                for (int c = 0; c < 4; ++c) {
                    u16x8 u = *(const u16x8*)&qk[(lb * 3 + p) * QS_STRIDE + co + c * 8];
                    #pragma unroll
                    for (int j = 0; j < 8; ++j) s += bf2f(u[j]) * qv[c * 8 + j];
                }
                s *= 0.17677669529663687f;        // 1/sqrt(32)
                sc[p] = s;
                mx = fmaxf(mx, s);
            }
        }
        float l = 0.f;
        #pragma unroll
        for (int p = 0; p < 3; ++p)
            if (p <= q) { sc[p] = __expf(sc[p] - mx); l += sc[p]; }
        const float inv = 1.f / l;

        #pragma unroll
        for (int c = 0; c < 4; ++c) {
            float z[8];
            #pragma unroll
            for (int j = 0; j < 8; ++j) z[j] = 0.f;
            #pragma unroll
            for (int p = 0; p < 3; ++p) {
                if (p <= q) {
                    u16x8 u = *(const u16x8*)&qk[(lb * 3 + p) * QS_STRIDE + 256 + co + c * 8];
                    #pragma unroll
                    for (int j = 0; j < 8; ++j) z[j] += sc[p] * bf2f(u[j]);
                }
            }
            u16x8 o;
            #pragma unroll
            for (int j = 0; j < 8; ++j) o[j] = f2bf(z[j] * inv);
            *(u16x8*)&xs[rq * XS_STRIDE + co + c * 8] = o;
        }
    }
    __syncthreads();

    // ---- Phase C: out[48][128] = z[48][128] @ Wo^T  (wave owns 1 n-tile)
    {
        bf16x8 az[3][4];
        #pragma unroll
        for (int m = 0; m < 3; ++m)
            #pragma unroll
            for (int k = 0; k < 4; ++k)
                az[m][k] = *(const bf16x8*)&xs[(m * 16 + lr) * XS_STRIDE + k * 32 + g * 8];

        const bf16x8* wop = (const bf16x8*)(wpk + QKV_PACK_ELEMS);
        const int nt = wave;
        bf16x8 b[4];
        #pragma unroll
        for (int k = 0; k < 4; ++k) b[k] = wop[(nt * 4 + k) * 64 + lane];

        const f32x4 zero4 = {0.f, 0.f, 0.f, 0.f};
        f32x4 acc[3];
        #pragma unroll
        for (int m = 0; m < 3; ++m) acc[m] = zero4;
        #pragma unroll
        for (int k = 0; k < 4; ++k)
            #pragma unroll
            for (int m = 0; m < 3; ++m)
                acc[m] = __builtin_amdgcn_mfma_f32_16x16x32_bf16(az[m][k], b[k], acc[m], 0, 0, 0);
        #pragma unroll
        for (int m = 0; m < 3; ++m)
            #pragma unroll
            for (int r = 0; r < 4; ++r) {
                size_t rg = row0 + (size_t)(m * 16 + g * 4 + r);
                __builtin_nontemporal_store(acc[m][r], &out[rg * DD + nt * 16 + lr]);
            }
    }
}

extern "C" void kernel_launch(void* const* d_in, const int* in_sizes, int n_in,
                              void* d_out, int out_size, void* d_ws, size_t ws_size,
                              hipStream_t stream) {
    const float* x  = (const float*)d_in[0];
    const float* Wk = (const float*)d_in[1];
    const float* Wq = (const float*)d_in[2];
    const float* Wv = (const float*)d_in[3];
    const float* Wo = (const float*)d_in[4];
    float* out = (float*)d_out;
    unsigned short* pk = (unsigned short*)d_ws;   // needs 131072 B

    pack_weights<<<(QKV_PACK_ELEMS + WO_PACK_ELEMS) / 256, 256, 0, stream>>>(Wk, Wq, Wv, Wo, pk);

    const int grid = BATCH * PP / RB;   // 8192
    attn_mfma<<<grid, THREADS, 0, stream>>>(x, pk, out);
}